// Round 9
// baseline (242.928 us; speedup 1.0000x reference)
//
#include <hip/hip_runtime.h>
#include <hip/hip_bf16.h>

// Problem constants
#define BS_   32
#define LQ_   300
#define LV_   13294
#define EMBED_ 256
#define HEADS_ 8
#define HEAD_DIM_ 32
#define NCHUNK_ 13294   /* 425408 rows / 32 rows per chunk */
#define PSTRIDE_ 512    /* persistent grid size */

typedef __attribute__((ext_vector_type(8))) short bf16x8;
typedef __attribute__((ext_vector_type(4))) float f32x4;

__device__ inline short f2bf(float f) {   // RNE fp32->bf16 (bit trick)
  union { float f; unsigned u; } x; x.f = f;
  return (short)((x.u + 0x7FFF + ((x.u >> 16) & 1)) >> 16);
}
__device__ inline short f2bf_i(float f) { // via HW cvt
  union { __hip_bfloat16 h; short s; } u;
  u.h = __float2bfloat16(f);
  return u.s;
}
__device__ inline float bf2f(short s) {
  union { unsigned u; float f; } x; x.u = ((unsigned)(unsigned short)s) << 16;
  return x.f;
}

// async global->LDS, 16B per lane. LDS dest = wave-uniform base + lane*16.
__device__ __forceinline__ void gld_lds16(const void* g, void* l) {
  __builtin_amdgcn_global_load_lds(
      (const __attribute__((address_space(1))) unsigned int*)g,
      (__attribute__((address_space(3))) unsigned int*)l, 16, 0, 0);
}

// ---------------------------------------------------------------------------
// W [256 k][Nsrc n] fp32 -> Wt [256 n][256 k] bf16, zero-padded cols >= Nsrc.
// ---------------------------------------------------------------------------
__global__ void convert_wt(const float* __restrict__ W, short* __restrict__ Wt,
                           int Nsrc) {
  const int n = blockIdx.x;   // 0..255
  const int k = threadIdx.x;  // 0..255
  Wt[n * 256 + k] = (n < Nsrc) ? f2bf(W[k * Nsrc + n]) : (short)0;
}

// Combined query-side weights: rows 0..255 = W_off cols, 256..383 = W_attn cols.
__global__ void convert_wq(const float* __restrict__ W_off,
                           const float* __restrict__ W_attn,
                           short* __restrict__ Wt) {
  const int n = blockIdx.x;   // 0..383
  const int k = threadIdx.x;  // 0..255
  Wt[n * 256 + k] = (n < 256) ? f2bf(W_off[k * 256 + n])
                              : f2bf(W_attn[k * 128 + (n - 256)]);
}

// ---------------------------------------------------------------------------
// Persistent chunk-pipelined value GEMM (unchanged from R8 - proven).
// Vp = bf16(value @ W_val + b_val), layout [b][h][pos][32].
// ---------------------------------------------------------------------------
__global__ __launch_bounds__(512, 2) void gemm_value_persist(
    const float* __restrict__ A, const short* __restrict__ Wt,
    const float* __restrict__ bias, short* __restrict__ Vp) {
  __shared__ float As[2][32 * 256];   // 2 x 32 KB

  const int tid = threadIdx.x;
  const int lane = tid & 63;
  const int w = tid >> 6;        // wave 0..7; also the head this wave owns
  const int lr = lane & 15;
  const int lkq = lane >> 4;     // k-quarter

  bf16x8 bfr[2][8];
#pragma unroll
  for (int nf = 0; nf < 2; ++nf) {
    const size_t bbase = (size_t)(w * 32 + nf * 16 + lr) * 256 + lkq * 8;
#pragma unroll
    for (int kt = 0; kt < 8; ++kt)
      bfr[nf][kt] = *(const bf16x8*)(Wt + bbase + kt * 32);
  }
  float bv[2];
#pragma unroll
  for (int nf = 0; nf < 2; ++nf) bv[nf] = bias[w * 32 + nf * 16 + lr];

  auto stage = [&](int buf, int c) {
    const float* src = A + (size_t)c * (32 * 256);
#pragma unroll
    for (int i = 0; i < 4; ++i) {
      const int r = w * 4 + i;
      gld_lds16(src + r * 256 + ((lane ^ (r & 7)) * 4), &As[buf][r * 256]);
    }
  };

  const int c0 = blockIdx.x;
  stage(0, c0);
  asm volatile("s_waitcnt vmcnt(0)" ::: "memory");
  __syncthreads();

  int cb = 0;
  for (int c = c0; c < NCHUNK_; c += PSTRIDE_) {
    const int nxt = c + PSTRIDE_;
    if (nxt < NCHUNK_) stage(cb ^ 1, nxt);

    f32x4 acc[2][2];
#pragma unroll
    for (int i = 0; i < 2; ++i)
#pragma unroll
      for (int jj = 0; jj < 2; ++jj) acc[i][jj] = (f32x4){0.f, 0.f, 0.f, 0.f};

    const float* as = &As[cb][0];
#pragma unroll
    for (int kt = 0; kt < 8; ++kt) {
      const int r0 = lr;
      const int r1 = 16 + lr;
      const int g = kt * 8 + lkq * 2;
      const f32x4 a00 = *(const f32x4*)(as + r0 * 256 + (((g    ) ^ (r0 & 7)) * 4));
      const f32x4 a01 = *(const f32x4*)(as + r0 * 256 + (((g + 1) ^ (r0 & 7)) * 4));
      const f32x4 a10 = *(const f32x4*)(as + r1 * 256 + (((g    ) ^ (r1 & 7)) * 4));
      const f32x4 a11 = *(const f32x4*)(as + r1 * 256 + (((g + 1) ^ (r1 & 7)) * 4));
      bf16x8 af0, af1;
#pragma unroll
      for (int i = 0; i < 4; ++i) {
        af0[i]     = f2bf_i(a00[i]);
        af0[i + 4] = f2bf_i(a01[i]);
        af1[i]     = f2bf_i(a10[i]);
        af1[i + 4] = f2bf_i(a11[i]);
      }
      acc[0][0] = __builtin_amdgcn_mfma_f32_16x16x32_bf16(af0, bfr[0][kt], acc[0][0], 0, 0, 0);
      acc[0][1] = __builtin_amdgcn_mfma_f32_16x16x32_bf16(af0, bfr[1][kt], acc[0][1], 0, 0, 0);
      acc[1][0] = __builtin_amdgcn_mfma_f32_16x16x32_bf16(af1, bfr[0][kt], acc[1][0], 0, 0, 0);
      acc[1][1] = __builtin_amdgcn_mfma_f32_16x16x32_bf16(af1, bfr[1][kt], acc[1][1], 0, 0, 0);
    }

#pragma unroll
    for (int mf = 0; mf < 2; ++mf)
#pragma unroll
      for (int rr = 0; rr < 4; ++rr) {
        const unsigned m = (unsigned)c * 32 + mf * 16 + lkq * 4 + rr;
        const unsigned b_ = m / LV_;
        const unsigned pos = m - b_ * LV_;
        const size_t rowbase = ((size_t)(b_ * HEADS_ + w) * LV_ + pos) * HEAD_DIM_;
#pragma unroll
        for (int nf = 0; nf < 2; ++nf)
          Vp[rowbase + nf * 16 + lr] = f2bf(acc[mf][nf][rr] + bv[nf]);
      }

    if (nxt < NCHUNK_) {
      asm volatile("s_waitcnt vmcnt(16)" ::: "memory");
      asm volatile("s_barrier" ::: "memory");
    }
    cb ^= 1;
  }
}

// ---------------------------------------------------------------------------
// Merged query projection: [offsets | logits] = query @ [W_off | W_attn].
// Block = 384 thr (6 waves): waves 0..3 -> offsets (256 cols, ldc 256),
// waves 4..5 -> logits (128 cols, ldc 128). A (64x256) staged once by
// waves 0..3; B slices in regs (bfr[4][8]); one barrier.
// ---------------------------------------------------------------------------
__global__ __launch_bounds__(384, 2) void gemm_qproj2(
    const float* __restrict__ A, const short* __restrict__ Wt,
    const float* __restrict__ b_off, const float* __restrict__ b_attn,
    float* __restrict__ offs, float* __restrict__ logits) {
  __shared__ float As[64 * 256];

  const int tid = threadIdx.x;
  const int lane = tid & 63;
  const int w = tid >> 6;          // 0..5
  const int n0 = w * 64;           // col in the combined 384-wide output
  const size_t m0 = (size_t)blockIdx.x * 64;
  const int lr = lane & 15;
  const int lkq = lane >> 4;

  if (w < 4) {
#pragma unroll
    for (int i = 0; i < 16; ++i) {
      const int row = w * 16 + i;
      gld_lds16(A + (m0 + row) * 256 + ((lane ^ (row & 7)) * 4), As + row * 256);
    }
  }

  bf16x8 bfr[4][8];
#pragma unroll
  for (int nf = 0; nf < 4; ++nf) {
    const size_t bbase = (size_t)(n0 + nf * 16 + lr) * 256 + lkq * 8;
#pragma unroll
    for (int kt = 0; kt < 8; ++kt)
      bfr[nf][kt] = *(const bf16x8*)(Wt + bbase + kt * 32);
  }

  f32x4 acc[4][4];
#pragma unroll
  for (int i = 0; i < 4; ++i)
#pragma unroll
    for (int jj = 0; jj < 4; ++jj) acc[i][jj] = (f32x4){0.f, 0.f, 0.f, 0.f};

  __syncthreads();

#pragma unroll
  for (int kt = 0; kt < 8; ++kt) {
#pragma unroll
    for (int mf = 0; mf < 4; ++mf) {
      const int row = mf * 16 + lr;
      const int gbase = kt * 8 + lkq * 2;
      const f32x4 a0 = *(const f32x4*)(As + row * 256 + ((gbase) ^ (row & 7)) * 4);
      const f32x4 a1 = *(const f32x4*)(As + row * 256 + ((gbase + 1) ^ (row & 7)) * 4);
      bf16x8 af;
#pragma unroll
      for (int i = 0; i < 4; ++i) {
        af[i]     = f2bf_i(a0[i]);
        af[i + 4] = f2bf_i(a1[i]);
      }
#pragma unroll
      for (int nf = 0; nf < 4; ++nf)
        acc[mf][nf] = __builtin_amdgcn_mfma_f32_16x16x32_bf16(af, bfr[nf][kt], acc[mf][nf], 0, 0, 0);
    }
  }

  float bv[4];
#pragma unroll
  for (int nf = 0; nf < 4; ++nf) {
    const int n = n0 + nf * 16 + lr;
    bv[nf] = (n < 256) ? b_off[n] : b_attn[n - 256];
  }
  const int lq4 = lkq * 4;
#pragma unroll
  for (int mf = 0; mf < 4; ++mf)
#pragma unroll
    for (int r = 0; r < 4; ++r) {
      const size_t m = m0 + mf * 16 + lq4 + r;
#pragma unroll
      for (int nf = 0; nf < 4; ++nf) {
        const int n = n0 + nf * 16 + lr;
        if (n < 256) offs[m * 256 + n] = acc[mf][nf][r] + bv[nf];
        else         logits[m * 128 + (n - 256)] = acc[mf][nf][r] + bv[nf];
      }
    }
}

// ---------------------------------------------------------------------------
// Final output projection (R6 bigA structure, f32 out).
// ---------------------------------------------------------------------------
__global__ __launch_bounds__(256, 2) void gemm_qproj(
    const float* __restrict__ A, const short* __restrict__ Wt,
    const float* __restrict__ bias, float* __restrict__ C) {
  __shared__ float As[64 * 256];

  const int tid = threadIdx.x;
  const int lane = tid & 63;
  const int w = tid >> 6;
  const int n0 = w * 64;
  const size_t m0 = (size_t)blockIdx.x * 64;
  const int lr = lane & 15;
  const int lkq = lane >> 4;

#pragma unroll
  for (int i = 0; i < 16; ++i) {
    const int row = w * 16 + i;
    gld_lds16(A + (m0 + row) * 256 + ((lane ^ (row & 7)) * 4), As + row * 256);
  }

  bf16x8 bfr[4][8];
#pragma unroll
  for (int nf = 0; nf < 4; ++nf) {
    const size_t bbase = (size_t)(n0 + nf * 16 + lr) * 256 + lkq * 8;
#pragma unroll
    for (int kt = 0; kt < 8; ++kt)
      bfr[nf][kt] = *(const bf16x8*)(Wt + bbase + kt * 32);
  }

  f32x4 acc[4][4];
#pragma unroll
  for (int i = 0; i < 4; ++i)
#pragma unroll
    for (int jj = 0; jj < 4; ++jj) acc[i][jj] = (f32x4){0.f, 0.f, 0.f, 0.f};

  __syncthreads();

#pragma unroll
  for (int kt = 0; kt < 8; ++kt) {
#pragma unroll
    for (int mf = 0; mf < 4; ++mf) {
      const int row = mf * 16 + lr;
      const int gbase = kt * 8 + lkq * 2;
      const f32x4 a0 = *(const f32x4*)(As + row * 256 + ((gbase) ^ (row & 7)) * 4);
      const f32x4 a1 = *(const f32x4*)(As + row * 256 + ((gbase + 1) ^ (row & 7)) * 4);
      bf16x8 af;
#pragma unroll
      for (int i = 0; i < 4; ++i) {
        af[i]     = f2bf_i(a0[i]);
        af[i + 4] = f2bf_i(a1[i]);
      }
#pragma unroll
      for (int nf = 0; nf < 4; ++nf)
        acc[mf][nf] = __builtin_amdgcn_mfma_f32_16x16x32_bf16(af, bfr[nf][kt], acc[mf][nf], 0, 0, 0);
    }
  }

  float bv[4];
#pragma unroll
  for (int nf = 0; nf < 4; ++nf) bv[nf] = bias[n0 + nf * 16 + lr];
  const int lq4 = lkq * 4;
#pragma unroll
  for (int mf = 0; mf < 4; ++mf)
#pragma unroll
    for (int r = 0; r < 4; ++r) {
      const size_t m = m0 + mf * 16 + lq4 + r;
#pragma unroll
      for (int nf = 0; nf < 4; ++nf) {
        const int n = n0 + nf * 16 + lr;
        C[m * 256 + n] = acc[mf][nf][r] + bv[nf];
      }
    }
}

// ---------------------------------------------------------------------------
// Fused softmax + deformable sampling.
// Thread per (row, head, 16-channel half): t -> c16=t&1, h=(t>>1)&7, row=t>>4.
// Softmax over the 16 logits computed in-register (x2 redundancy, cheap);
// per corner: 2x bf16x8 (32 B) gathers; acc[16] f32.
// ---------------------------------------------------------------------------
__global__ __launch_bounds__(256) void msda_sample_fused(
    const float* __restrict__ ref_pts,   // [BS*LQ, 4, 2]
    const float* __restrict__ offsets,   // [BS*LQ, 256]  (h,l,p,2)
    const float* __restrict__ logits,    // [BS*LQ, 128]  (h,l,p)
    const short* __restrict__ value_p,   // [b,h,pos,32] bf16
    float* __restrict__ tmp)             // [BS*LQ, 256]
{
  const int t = blockIdx.x * 256 + threadIdx.x;
  const int c16 = t & 1;                // channel half: c = c16*16
  const int h = (t >> 1) & 7;
  const int row = t >> 4;               // b*LQ + q
  const int b = row / LQ_;

  const int HS[4] = {100, 50, 25, 13};
  const int START[4] = {0, 10000, 12500, 13125};

  // ---- softmax over 16 logits, in-register ----
  const float* lg = logits + (size_t)row * 128 + h * 16;
  float wv[16];
  float mx = -1e30f;
#pragma unroll
  for (int i = 0; i < 4; ++i) {
    const f32x4 v = *(const f32x4*)(lg + i * 4);
#pragma unroll
    for (int jj = 0; jj < 4; ++jj) { wv[i * 4 + jj] = v[jj]; mx = fmaxf(mx, v[jj]); }
  }
  float sum = 0.f;
#pragma unroll
  for (int i = 0; i < 16; ++i) { wv[i] = __expf(wv[i] - mx); sum += wv[i]; }
  const float inv = 1.0f / sum;
#pragma unroll
  for (int i = 0; i < 16; ++i) wv[i] *= inv;

  const float* offr = offsets + (size_t)row * 256 + h * 32;
  const float* refr = ref_pts + (size_t)row * 8;

  float acc[16];
#pragma unroll
  for (int jj = 0; jj < 16; ++jj) acc[jj] = 0.f;

#pragma unroll
  for (int l = 0; l < 4; ++l) {
    const int HH = HS[l];
    const int WW = HS[l];
    const float fH = (float)HH, fW = (float)WW;
    const float rx = refr[l * 2 + 0];
    const float ry = refr[l * 2 + 1];
    const short* vbase =
        value_p + ((size_t)(b * HEADS_ + h) * LV_ + START[l]) * HEAD_DIM_ + c16 * 16;
#pragma unroll
    for (int p = 0; p < 4; ++p) {
      const float ox = offr[(l * 4 + p) * 2 + 0];
      const float oy = offr[(l * 4 + p) * 2 + 1];
      const float x = (rx + ox / fW) * fW - 0.5f;
      const float y = (ry + oy / fH) * fH - 0.5f;
      const float x0f = floorf(x), y0f = floorf(y);
      const float fx = x - x0f, fy = y - y0f;
      const int x0 = (int)x0f, y0 = (int)y0f;
      const float wgt = wv[l * 4 + p];
      const float iy0 = (y0 >= 0 && y0 < HH) ? 1.f : 0.f;
      const float iy1 = (y0 + 1 >= 0 && y0 + 1 < HH) ? 1.f : 0.f;
      const float ix0 = (x0 >= 0 && x0 < WW) ? 1.f : 0.f;
      const float ix1 = (x0 + 1 >= 0 && x0 + 1 < WW) ? 1.f : 0.f;
      const float w00 = (1.f - fy) * (1.f - fx) * wgt * iy0 * ix0;
      const float w01 = (1.f - fy) * fx * wgt * iy0 * ix1;
      const float w10 = fy * (1.f - fx) * wgt * iy1 * ix0;
      const float w11 = fy * fx * wgt * iy1 * ix1;
      const int xc0 = min(max(x0, 0), WW - 1);
      const int xc1 = min(max(x0 + 1, 0), WW - 1);
      const int yc0 = min(max(y0, 0), HH - 1);
      const int yc1 = min(max(y0 + 1, 0), HH - 1);
      const short* p00 = vbase + (size_t)(yc0 * WW + xc0) * HEAD_DIM_;
      const short* p01 = vbase + (size_t)(yc0 * WW + xc1) * HEAD_DIM_;
      const short* p10 = vbase + (size_t)(yc1 * WW + xc0) * HEAD_DIM_;
      const short* p11 = vbase + (size_t)(yc1 * WW + xc1) * HEAD_DIM_;
      const bf16x8 q00a = *(const bf16x8*)(p00);
      const bf16x8 q00b = *(const bf16x8*)(p00 + 8);
      const bf16x8 q01a = *(const bf16x8*)(p01);
      const bf16x8 q01b = *(const bf16x8*)(p01 + 8);
      const bf16x8 q10a = *(const bf16x8*)(p10);
      const bf16x8 q10b = *(const bf16x8*)(p10 + 8);
      const bf16x8 q11a = *(const bf16x8*)(p11);
      const bf16x8 q11b = *(const bf16x8*)(p11 + 8);
#pragma unroll
      for (int jj = 0; jj < 8; ++jj) {
        acc[jj] += w00 * bf2f(q00a[jj]) + w01 * bf2f(q01a[jj]) +
                   w10 * bf2f(q10a[jj]) + w11 * bf2f(q11a[jj]);
        acc[jj + 8] += w00 * bf2f(q00b[jj]) + w01 * bf2f(q01b[jj]) +
                       w10 * bf2f(q10b[jj]) + w11 * bf2f(q11b[jj]);
      }
    }
  }
  float* o = tmp + (size_t)row * 256 + h * 32 + c16 * 16;
#pragma unroll
  for (int i = 0; i < 4; ++i) {
    f32x4 v = {acc[i * 4], acc[i * 4 + 1], acc[i * 4 + 2], acc[i * 4 + 3]};
    *(f32x4*)(o + i * 4) = v;
  }
}

// ---------------------------------------------------------------------------
extern "C" void kernel_launch(void* const* d_in, const int* in_sizes, int n_in,
                              void* d_out, int out_size, void* d_ws, size_t ws_size,
                              hipStream_t stream) {
  const float* query  = (const float*)d_in[0];
  const float* refpts = (const float*)d_in[1];
  const float* value  = (const float*)d_in[2];
  const float* W_off  = (const float*)d_in[4];
  const float* b_off  = (const float*)d_in[5];
  const float* W_attn = (const float*)d_in[6];
  const float* b_attn = (const float*)d_in[7];
  const float* W_val  = (const float*)d_in[8];
  const float* b_val  = (const float*)d_in[9];
  const float* W_out  = (const float*)d_in[10];
  const float* b_out  = (const float*)d_in[11];
  float* out = (float*)d_out;

  char* ws = (char*)d_ws;
  short* value_p = (short*)ws;                                 // 217,710,592 B
  size_t off = (size_t)BS_ * HEADS_ * LV_ * HEAD_DIM_ * 2;
  float* offsets = (float*)(ws + off); off += (size_t)BS_ * LQ_ * 256 * 4;
  float* logits  = (float*)(ws + off); off += (size_t)BS_ * LQ_ * 128 * 4;
  float* tmp     = (float*)(ws + off); off += (size_t)BS_ * LQ_ * 256 * 4;

  // Aliasing plan (stream-sequential ordering makes each safe):
  //  WtQ (384x256 bf16 = 192 KB) in value_p[0:192KB): consumed by the merged
  //    query GEMM BEFORE the value GEMM overwrites value_p.
  //  WtV = tmp[0:128KB): consumed by the value GEMM (B-reg prologue + L2);
  //    overwritten by the sampler's output afterwards.
  //  WtO = value_p[0:128KB): written AFTER the sampler has read value_p.
  short* WtQ = (short*)value_p;
  short* WtV = (short*)tmp;
  short* WtO = (short*)value_p;

  const int MQ = BS_ * LQ_;   // 9600 = 64*150

  convert_wq<<<384, 256, 0, stream>>>(W_off, W_attn, WtQ);
  gemm_qproj2<<<MQ / 64, 384, 0, stream>>>(query, WtQ, b_off, b_attn, offsets, logits);
  convert_wt<<<256, 256, 0, stream>>>(W_val, WtV, 256);
  gemm_value_persist<<<PSTRIDE_, 512, 0, stream>>>(value, WtV, b_val, value_p);
  msda_sample_fused<<<(MQ * 16) / 256, 256, 0, stream>>>(refpts, offsets, logits, value_p, tmp);
  convert_wt<<<256, 256, 0, stream>>>(W_out, WtO, 256);
  gemm_qproj<<<MQ / 64, 256, 0, stream>>>(tmp, WtO, b_out, out);
}

// Round 10
// 210.822 us; speedup vs baseline: 1.1523x; 1.1523x over previous
//
#include <hip/hip_runtime.h>
#include <hip/hip_bf16.h>

// Problem constants
#define BS_   32
#define LQ_   300
#define LV_   13294
#define EMBED_ 256
#define HEADS_ 8
#define HEAD_DIM_ 32
#define NCHUNK_ 13294   /* 425408 rows / 32 rows per chunk */
#define PSTRIDE_ 512    /* persistent grid size */

typedef __attribute__((ext_vector_type(8))) short bf16x8;
typedef __attribute__((ext_vector_type(4))) float f32x4;

__device__ inline short f2bf(float f) {   // RNE fp32->bf16 (bit trick)
  union { float f; unsigned u; } x; x.f = f;
  return (short)((x.u + 0x7FFF + ((x.u >> 16) & 1)) >> 16);
}
__device__ inline short f2bf_i(float f) { // via HW cvt
  union { __hip_bfloat16 h; short s; } u;
  u.h = __float2bfloat16(f);
  return u.s;
}
__device__ inline float bf2f(short s) {
  union { unsigned u; float f; } x; x.u = ((unsigned)(unsigned short)s) << 16;
  return x.f;
}

// async global->LDS, 16B per lane. LDS dest = wave-uniform base + lane*16.
__device__ __forceinline__ void gld_lds16(const void* g, void* l) {
  __builtin_amdgcn_global_load_lds(
      (const __attribute__((address_space(1))) unsigned int*)g,
      (__attribute__((address_space(3))) unsigned int*)l, 16, 0, 0);
}

// ---------------------------------------------------------------------------
// One up-front transpose+convert for ALL weights (dedicated ws slots):
//   blocks   0..383: WtQ row n   <- W_off col n (n<256) | W_attn col n-256
//   blocks 384..639: WtV row n-384 <- W_val col
//   blocks 640..895: WtO row n-640 <- W_out col
// ---------------------------------------------------------------------------
__global__ void convert_all(const float* __restrict__ W_off,
                            const float* __restrict__ W_attn,
                            const float* __restrict__ W_val,
                            const float* __restrict__ W_out,
                            short* __restrict__ WtQ,
                            short* __restrict__ WtV,
                            short* __restrict__ WtO) {
  const int n = blockIdx.x;
  const int k = threadIdx.x;
  if (n < 384) {
    WtQ[n * 256 + k] = (n < 256) ? f2bf(W_off[k * 256 + n])
                                 : f2bf(W_attn[k * 128 + (n - 256)]);
  } else if (n < 640) {
    WtV[(n - 384) * 256 + k] = f2bf(W_val[k * 256 + (n - 384)]);
  } else {
    WtO[(n - 640) * 256 + k] = f2bf(W_out[k * 256 + (n - 640)]);
  }
}

// ---------------------------------------------------------------------------
// Persistent chunk-pipelined value GEMM (R8, proven).
// Vp = bf16(value @ W_val + b_val), layout [b][h][pos][32].
// ---------------------------------------------------------------------------
__global__ __launch_bounds__(512, 2) void gemm_value_persist(
    const float* __restrict__ A, const short* __restrict__ Wt,
    const float* __restrict__ bias, short* __restrict__ Vp) {
  __shared__ float As[2][32 * 256];   // 2 x 32 KB

  const int tid = threadIdx.x;
  const int lane = tid & 63;
  const int w = tid >> 6;        // wave 0..7; also the head this wave owns
  const int lr = lane & 15;
  const int lkq = lane >> 4;     // k-quarter

  bf16x8 bfr[2][8];
#pragma unroll
  for (int nf = 0; nf < 2; ++nf) {
    const size_t bbase = (size_t)(w * 32 + nf * 16 + lr) * 256 + lkq * 8;
#pragma unroll
    for (int kt = 0; kt < 8; ++kt)
      bfr[nf][kt] = *(const bf16x8*)(Wt + bbase + kt * 32);
  }
  float bv[2];
#pragma unroll
  for (int nf = 0; nf < 2; ++nf) bv[nf] = bias[w * 32 + nf * 16 + lr];

  auto stage = [&](int buf, int c) {
    const float* src = A + (size_t)c * (32 * 256);
#pragma unroll
    for (int i = 0; i < 4; ++i) {
      const int r = w * 4 + i;
      gld_lds16(src + r * 256 + ((lane ^ (r & 7)) * 4), &As[buf][r * 256]);
    }
  };

  const int c0 = blockIdx.x;
  stage(0, c0);
  asm volatile("s_waitcnt vmcnt(0)" ::: "memory");
  __syncthreads();

  int cb = 0;
  for (int c = c0; c < NCHUNK_; c += PSTRIDE_) {
    const int nxt = c + PSTRIDE_;
    if (nxt < NCHUNK_) stage(cb ^ 1, nxt);

    f32x4 acc[2][2];
#pragma unroll
    for (int i = 0; i < 2; ++i)
#pragma unroll
      for (int jj = 0; jj < 2; ++jj) acc[i][jj] = (f32x4){0.f, 0.f, 0.f, 0.f};

    const float* as = &As[cb][0];
#pragma unroll
    for (int kt = 0; kt < 8; ++kt) {
      const int r0 = lr;
      const int r1 = 16 + lr;
      const int g = kt * 8 + lkq * 2;
      const f32x4 a00 = *(const f32x4*)(as + r0 * 256 + (((g    ) ^ (r0 & 7)) * 4));
      const f32x4 a01 = *(const f32x4*)(as + r0 * 256 + (((g + 1) ^ (r0 & 7)) * 4));
      const f32x4 a10 = *(const f32x4*)(as + r1 * 256 + (((g    ) ^ (r1 & 7)) * 4));
      const f32x4 a11 = *(const f32x4*)(as + r1 * 256 + (((g + 1) ^ (r1 & 7)) * 4));
      bf16x8 af0, af1;
#pragma unroll
      for (int i = 0; i < 4; ++i) {
        af0[i]     = f2bf_i(a00[i]);
        af0[i + 4] = f2bf_i(a01[i]);
        af1[i]     = f2bf_i(a10[i]);
        af1[i + 4] = f2bf_i(a11[i]);
      }
      acc[0][0] = __builtin_amdgcn_mfma_f32_16x16x32_bf16(af0, bfr[0][kt], acc[0][0], 0, 0, 0);
      acc[0][1] = __builtin_amdgcn_mfma_f32_16x16x32_bf16(af0, bfr[1][kt], acc[0][1], 0, 0, 0);
      acc[1][0] = __builtin_amdgcn_mfma_f32_16x16x32_bf16(af1, bfr[0][kt], acc[1][0], 0, 0, 0);
      acc[1][1] = __builtin_amdgcn_mfma_f32_16x16x32_bf16(af1, bfr[1][kt], acc[1][1], 0, 0, 0);
    }

#pragma unroll
    for (int mf = 0; mf < 2; ++mf)
#pragma unroll
      for (int rr = 0; rr < 4; ++rr) {
        const unsigned m = (unsigned)c * 32 + mf * 16 + lkq * 4 + rr;
        const unsigned b_ = m / LV_;
        const unsigned pos = m - b_ * LV_;
        const size_t rowbase = ((size_t)(b_ * HEADS_ + w) * LV_ + pos) * HEAD_DIM_;
#pragma unroll
        for (int nf = 0; nf < 2; ++nf)
          Vp[rowbase + nf * 16 + lr] = f2bf(acc[mf][nf][rr] + bv[nf]);
      }

    if (nxt < NCHUNK_) {
      asm volatile("s_waitcnt vmcnt(16)" ::: "memory");
      asm volatile("s_barrier" ::: "memory");
    }
    cb ^= 1;
  }
}

// ---------------------------------------------------------------------------
// Merged query projection: [offsets | logits] = query @ [W_off | W_attn].
// ---------------------------------------------------------------------------
__global__ __launch_bounds__(384, 2) void gemm_qproj2(
    const float* __restrict__ A, const short* __restrict__ Wt,
    const float* __restrict__ b_off, const float* __restrict__ b_attn,
    float* __restrict__ offs, float* __restrict__ logits) {
  __shared__ float As[64 * 256];

  const int tid = threadIdx.x;
  const int lane = tid & 63;
  const int w = tid >> 6;          // 0..5
  const int n0 = w * 64;
  const size_t m0 = (size_t)blockIdx.x * 64;
  const int lr = lane & 15;
  const int lkq = lane >> 4;

  if (w < 4) {
#pragma unroll
    for (int i = 0; i < 16; ++i) {
      const int row = w * 16 + i;
      gld_lds16(A + (m0 + row) * 256 + ((lane ^ (row & 7)) * 4), As + row * 256);
    }
  }

  bf16x8 bfr[4][8];
#pragma unroll
  for (int nf = 0; nf < 4; ++nf) {
    const size_t bbase = (size_t)(n0 + nf * 16 + lr) * 256 + lkq * 8;
#pragma unroll
    for (int kt = 0; kt < 8; ++kt)
      bfr[nf][kt] = *(const bf16x8*)(Wt + bbase + kt * 32);
  }

  f32x4 acc[4][4];
#pragma unroll
  for (int i = 0; i < 4; ++i)
#pragma unroll
    for (int jj = 0; jj < 4; ++jj) acc[i][jj] = (f32x4){0.f, 0.f, 0.f, 0.f};

  __syncthreads();

#pragma unroll
  for (int kt = 0; kt < 8; ++kt) {
#pragma unroll
    for (int mf = 0; mf < 4; ++mf) {
      const int row = mf * 16 + lr;
      const int gbase = kt * 8 + lkq * 2;
      const f32x4 a0 = *(const f32x4*)(As + row * 256 + ((gbase) ^ (row & 7)) * 4);
      const f32x4 a1 = *(const f32x4*)(As + row * 256 + ((gbase + 1) ^ (row & 7)) * 4);
      bf16x8 af;
#pragma unroll
      for (int i = 0; i < 4; ++i) {
        af[i]     = f2bf_i(a0[i]);
        af[i + 4] = f2bf_i(a1[i]);
      }
#pragma unroll
      for (int nf = 0; nf < 4; ++nf)
        acc[mf][nf] = __builtin_amdgcn_mfma_f32_16x16x32_bf16(af, bfr[nf][kt], acc[mf][nf], 0, 0, 0);
    }
  }

  float bv[4];
#pragma unroll
  for (int nf = 0; nf < 4; ++nf) {
    const int n = n0 + nf * 16 + lr;
    bv[nf] = (n < 256) ? b_off[n] : b_attn[n - 256];
  }
  const int lq4 = lkq * 4;
#pragma unroll
  for (int mf = 0; mf < 4; ++mf)
#pragma unroll
    for (int r = 0; r < 4; ++r) {
      const size_t m = m0 + mf * 16 + lq4 + r;
#pragma unroll
      for (int nf = 0; nf < 4; ++nf) {
        const int n = n0 + nf * 16 + lr;
        if (n < 256) offs[m * 256 + n] = acc[mf][nf][r] + bv[nf];
        else         logits[m * 128 + (n - 256)] = acc[mf][nf][r] + bv[nf];
      }
    }
}

// ---------------------------------------------------------------------------
// Final output projection (R6 bigA structure, f32 out).
// ---------------------------------------------------------------------------
__global__ __launch_bounds__(256, 2) void gemm_qproj(
    const float* __restrict__ A, const short* __restrict__ Wt,
    const float* __restrict__ bias, float* __restrict__ C) {
  __shared__ float As[64 * 256];

  const int tid = threadIdx.x;
  const int lane = tid & 63;
  const int w = tid >> 6;
  const int n0 = w * 64;
  const size_t m0 = (size_t)blockIdx.x * 64;
  const int lr = lane & 15;
  const int lkq = lane >> 4;

#pragma unroll
  for (int i = 0; i < 16; ++i) {
    const int row = w * 16 + i;
    gld_lds16(A + (m0 + row) * 256 + ((lane ^ (row & 7)) * 4), As + row * 256);
  }

  bf16x8 bfr[4][8];
#pragma unroll
  for (int nf = 0; nf < 4; ++nf) {
    const size_t bbase = (size_t)(n0 + nf * 16 + lr) * 256 + lkq * 8;
#pragma unroll
    for (int kt = 0; kt < 8; ++kt)
      bfr[nf][kt] = *(const bf16x8*)(Wt + bbase + kt * 32);
  }

  f32x4 acc[4][4];
#pragma unroll
  for (int i = 0; i < 4; ++i)
#pragma unroll
    for (int jj = 0; jj < 4; ++jj) acc[i][jj] = (f32x4){0.f, 0.f, 0.f, 0.f};

  __syncthreads();

#pragma unroll
  for (int kt = 0; kt < 8; ++kt) {
#pragma unroll
    for (int mf = 0; mf < 4; ++mf) {
      const int row = mf * 16 + lr;
      const int gbase = kt * 8 + lkq * 2;
      const f32x4 a0 = *(const f32x4*)(As + row * 256 + ((gbase) ^ (row & 7)) * 4);
      const f32x4 a1 = *(const f32x4*)(As + row * 256 + ((gbase + 1) ^ (row & 7)) * 4);
      bf16x8 af;
#pragma unroll
      for (int i = 0; i < 4; ++i) {
        af[i]     = f2bf_i(a0[i]);
        af[i + 4] = f2bf_i(a1[i]);
      }
#pragma unroll
      for (int nf = 0; nf < 4; ++nf)
        acc[mf][nf] = __builtin_amdgcn_mfma_f32_16x16x32_bf16(af, bfr[nf][kt], acc[mf][nf], 0, 0, 0);
    }
  }

  float bv[4];
#pragma unroll
  for (int nf = 0; nf < 4; ++nf) bv[nf] = bias[n0 + nf * 16 + lr];
  const int lq4 = lkq * 4;
#pragma unroll
  for (int mf = 0; mf < 4; ++mf)
#pragma unroll
    for (int r = 0; r < 4; ++r) {
      const size_t m = m0 + mf * 16 + lq4 + r;
#pragma unroll
      for (int nf = 0; nf < 4; ++nf) {
        const int n = n0 + nf * 16 + lr;
        C[m * 256 + n] = acc[mf][nf][r] + bv[nf];
      }
    }
}

// ---------------------------------------------------------------------------
// Fused softmax + deformable sampling, 8-channel threads (max TLP).
// Thread t -> c8 = t&3 (channel octet), h = (t>>2)&7, row = t>>5.
// Softmax over 16 logits in-register (x4 redundant; ~64 VALU cyc, trivial
// vs gather latency). Per corner: one bf16x8 (16 B) gather.
// ---------------------------------------------------------------------------
__global__ __launch_bounds__(256) void msda_sample_fused(
    const float* __restrict__ ref_pts,   // [BS*LQ, 4, 2]
    const float* __restrict__ offsets,   // [BS*LQ, 256]  (h,l,p,2)
    const float* __restrict__ logits,    // [BS*LQ, 128]  (h,l,p)
    const short* __restrict__ value_p,   // [b,h,pos,32] bf16
    float* __restrict__ tmp)             // [BS*LQ, 256]
{
  const int t = blockIdx.x * 256 + threadIdx.x;
  const int c8 = t & 3;
  const int h = (t >> 2) & 7;
  const int row = t >> 5;
  const int b = row / LQ_;

  const int HS[4] = {100, 50, 25, 13};
  const int START[4] = {0, 10000, 12500, 13125};

  // ---- softmax over 16 logits, in-register ----
  const float* lg = logits + (size_t)row * 128 + h * 16;
  float wv[16];
  float mx = -1e30f;
#pragma unroll
  for (int i = 0; i < 4; ++i) {
    const f32x4 v = *(const f32x4*)(lg + i * 4);
#pragma unroll
    for (int jj = 0; jj < 4; ++jj) { wv[i * 4 + jj] = v[jj]; mx = fmaxf(mx, v[jj]); }
  }
  float sum = 0.f;
#pragma unroll
  for (int i = 0; i < 16; ++i) { wv[i] = __expf(wv[i] - mx); sum += wv[i]; }
  const float inv = 1.0f / sum;
#pragma unroll
  for (int i = 0; i < 16; ++i) wv[i] *= inv;

  const float* offr = offsets + (size_t)row * 256 + h * 32;
  const float* refr = ref_pts + (size_t)row * 8;

  float acc[8];
#pragma unroll
  for (int jj = 0; jj < 8; ++jj) acc[jj] = 0.f;

#pragma unroll
  for (int l = 0; l < 4; ++l) {
    const int HH = HS[l];
    const int WW = HS[l];
    const float fH = (float)HH, fW = (float)WW;
    const float rx = refr[l * 2 + 0];
    const float ry = refr[l * 2 + 1];
    const short* vbase =
        value_p + ((size_t)(b * HEADS_ + h) * LV_ + START[l]) * HEAD_DIM_ + c8 * 8;
#pragma unroll
    for (int p = 0; p < 4; ++p) {
      const float ox = offr[(l * 4 + p) * 2 + 0];
      const float oy = offr[(l * 4 + p) * 2 + 1];
      const float x = (rx + ox / fW) * fW - 0.5f;
      const float y = (ry + oy / fH) * fH - 0.5f;
      const float x0f = floorf(x), y0f = floorf(y);
      const float fx = x - x0f, fy = y - y0f;
      const int x0 = (int)x0f, y0 = (int)y0f;
      const float wgt = wv[l * 4 + p];
      const float iy0 = (y0 >= 0 && y0 < HH) ? 1.f : 0.f;
      const float iy1 = (y0 + 1 >= 0 && y0 + 1 < HH) ? 1.f : 0.f;
      const float ix0 = (x0 >= 0 && x0 < WW) ? 1.f : 0.f;
      const float ix1 = (x0 + 1 >= 0 && x0 + 1 < WW) ? 1.f : 0.f;
      const float w00 = (1.f - fy) * (1.f - fx) * wgt * iy0 * ix0;
      const float w01 = (1.f - fy) * fx * wgt * iy0 * ix1;
      const float w10 = fy * (1.f - fx) * wgt * iy1 * ix0;
      const float w11 = fy * fx * wgt * iy1 * ix1;
      const int xc0 = min(max(x0, 0), WW - 1);
      const int xc1 = min(max(x0 + 1, 0), WW - 1);
      const int yc0 = min(max(y0, 0), HH - 1);
      const int yc1 = min(max(y0 + 1, 0), HH - 1);
      const bf16x8 q00 = *(const bf16x8*)(vbase + (size_t)(yc0 * WW + xc0) * HEAD_DIM_);
      const bf16x8 q01 = *(const bf16x8*)(vbase + (size_t)(yc0 * WW + xc1) * HEAD_DIM_);
      const bf16x8 q10 = *(const bf16x8*)(vbase + (size_t)(yc1 * WW + xc0) * HEAD_DIM_);
      const bf16x8 q11 = *(const bf16x8*)(vbase + (size_t)(yc1 * WW + xc1) * HEAD_DIM_);
#pragma unroll
      for (int jj = 0; jj < 8; ++jj) {
        acc[jj] += w00 * bf2f(q00[jj]) + w01 * bf2f(q01[jj]) +
                   w10 * bf2f(q10[jj]) + w11 * bf2f(q11[jj]);
      }
    }
  }
  float* o = tmp + (size_t)row * 256 + h * 32 + c8 * 8;
  f32x4 o0 = {acc[0], acc[1], acc[2], acc[3]};
  f32x4 o1 = {acc[4], acc[5], acc[6], acc[7]};
  *(f32x4*)(o) = o0;
  *(f32x4*)(o + 4) = o1;
}

// ---------------------------------------------------------------------------
extern "C" void kernel_launch(void* const* d_in, const int* in_sizes, int n_in,
                              void* d_out, int out_size, void* d_ws, size_t ws_size,
                              hipStream_t stream) {
  const float* query  = (const float*)d_in[0];
  const float* refpts = (const float*)d_in[1];
  const float* value  = (const float*)d_in[2];
  const float* W_off  = (const float*)d_in[4];
  const float* b_off  = (const float*)d_in[5];
  const float* W_attn = (const float*)d_in[6];
  const float* b_attn = (const float*)d_in[7];
  const float* W_val  = (const float*)d_in[8];
  const float* b_val  = (const float*)d_in[9];
  const float* W_out  = (const float*)d_in[10];
  const float* b_out  = (const float*)d_in[11];
  float* out = (float*)d_out;

  // Dedicated workspace slots -- no aliasing. Total 242.7 MB (< proven ws).
  char* ws = (char*)d_ws;
  short* value_p = (short*)ws;                                 // 217,710,592 B
  size_t off = (size_t)BS_ * HEADS_ * LV_ * HEAD_DIM_ * 2;
  float* offsets = (float*)(ws + off); off += (size_t)BS_ * LQ_ * 256 * 4;  // 9.83 MB
  float* logits  = (float*)(ws + off); off += (size_t)BS_ * LQ_ * 128 * 4;  // 4.92 MB
  float* tmp     = (float*)(ws + off); off += (size_t)BS_ * LQ_ * 256 * 4;  // 9.83 MB
  short* WtQ = (short*)(ws + off); off += 384 * 256 * 2;                    // 192 KB
  short* WtV = (short*)(ws + off); off += 256 * 256 * 2;                    // 128 KB
  short* WtO = (short*)(ws + off); off += 256 * 256 * 2;                    // 128 KB

  const int MQ = BS_ * LQ_;   // 9600 = 64*150

  convert_all<<<896, 256, 0, stream>>>(W_off, W_attn, W_val, W_out, WtQ, WtV, WtO);
  gemm_qproj2<<<MQ / 64, 384, 0, stream>>>(query, WtQ, b_off, b_attn, offsets, logits);
  gemm_value_persist<<<PSTRIDE_, 512, 0, stream>>>(value, WtV, b_val, value_p);
  msda_sample_fused<<<(MQ * 32) / 256, 256, 0, stream>>>(refpts, offsets, logits, value_p, tmp);
  gemm_qproj<<<MQ / 64, 256, 0, stream>>>(tmp, WtO, b_out, out);
}

// Round 11
// 206.050 us; speedup vs baseline: 1.1790x; 1.0232x over previous
//
#include <hip/hip_runtime.h>
#include <hip/hip_bf16.h>

// Problem constants
#define BS_   32
#define LQ_   300
#define LV_   13294
#define EMBED_ 256
#define HEADS_ 8
#define HEAD_DIM_ 32
#define NCHUNK_ 13294   /* 425408 rows / 32 rows per chunk */
#define PSTRIDE_ 512    /* persistent grid size */

typedef __attribute__((ext_vector_type(8))) short bf16x8;
typedef __attribute__((ext_vector_type(4))) float f32x4;

__device__ inline short f2bf(float f) {   // RNE fp32->bf16 (bit trick)
  union { float f; unsigned u; } x; x.f = f;
  return (short)((x.u + 0x7FFF + ((x.u >> 16) & 1)) >> 16);
}
__device__ inline short f2bf_i(float f) { // via HW cvt
  union { __hip_bfloat16 h; short s; } u;
  u.h = __float2bfloat16(f);
  return u.s;
}
__device__ inline float bf2f(short s) {
  union { unsigned u; float f; } x; x.u = ((unsigned)(unsigned short)s) << 16;
  return x.f;
}

// async global->LDS, 16B per lane. LDS dest = wave-uniform base + lane*16.
__device__ __forceinline__ void gld_lds16(const void* g, void* l) {
  __builtin_amdgcn_global_load_lds(
      (const __attribute__((address_space(1))) unsigned int*)g,
      (__attribute__((address_space(3))) unsigned int*)l, 16, 0, 0);
}

// ---------------------------------------------------------------------------
// One up-front transpose+convert for ALL weights (dedicated ws slots).
// ---------------------------------------------------------------------------
__global__ void convert_all(const float* __restrict__ W_off,
                            const float* __restrict__ W_attn,
                            const float* __restrict__ W_val,
                            const float* __restrict__ W_out,
                            short* __restrict__ WtQ,
                            short* __restrict__ WtV,
                            short* __restrict__ WtO) {
  const int n = blockIdx.x;
  const int k = threadIdx.x;
  if (n < 384) {
    WtQ[n * 256 + k] = (n < 256) ? f2bf(W_off[k * 256 + n])
                                 : f2bf(W_attn[k * 128 + (n - 256)]);
  } else if (n < 640) {
    WtV[(n - 384) * 256 + k] = f2bf(W_val[k * 256 + (n - 384)]);
  } else {
    WtO[(n - 640) * 256 + k] = f2bf(W_out[k * 256 + (n - 640)]);
  }
}

// ---------------------------------------------------------------------------
// Mega GEMM kernel: 512 blocks x 512 thr (8 waves), launch_bounds(512,2).
// Phase 1 (blocks 0..149 only): merged query projection tile
//   [offsets | logits](64 rows) = query_tile @ WtQ^T. A staged in the shared
//   64 KB LDS; B fragments read per-use from L2-resident WtQ (192 KB) to
//   stay under the 128-VGPR cap. Waves 0..5 compute (384 cols / 64 each).
// Phase 2 (ALL 512 blocks): R8's persistent chunk-pipelined value GEMM,
//   unchanged: Vp = bf16(value @ W_val + b_val), layout [b][h][pos][32];
//   2-deep 32 KB LDS ring in the same 64 KB buffer; counted vmcnt(16).
// Phase-1 blocks start phase 2 ~4 us late; the other 362 proceed at once,
// so the query projection hides entirely under the HBM-bound value GEMM.
// ---------------------------------------------------------------------------
__global__ __launch_bounds__(512, 2) void mega_gemm(
    const float* __restrict__ value, const short* __restrict__ WtV,
    const float* __restrict__ b_val, short* __restrict__ Vp,
    const float* __restrict__ query, const short* __restrict__ WtQ,
    const float* __restrict__ b_off, const float* __restrict__ b_attn,
    float* __restrict__ offs, float* __restrict__ logits) {
  __shared__ float As[16384];   // 64 KB, shared by both phases

  const int tid = threadIdx.x;
  const int lane = tid & 63;
  const int w = tid >> 6;        // wave 0..7
  const int lr = lane & 15;
  const int lkq = lane >> 4;     // k-quarter
  const int bid = blockIdx.x;

  // ================= phase 1: query projection (blocks 0..149) ============
  if (bid < 150) {
    const size_t m0 = (size_t)bid * 64;
    // stage query tile: 8 waves x 8 rows (row = 1 KB per instr)
#pragma unroll
    for (int i = 0; i < 8; ++i) {
      const int row = w * 8 + i;
      gld_lds16(query + (m0 + row) * 256 + ((lane ^ (row & 7)) * 4), As + row * 256);
    }
    __syncthreads();   // drains vmcnt(0) + barrier

    if (w < 6) {
      const int n0 = w * 64;
      f32x4 acc[4][4];
#pragma unroll
      for (int i = 0; i < 4; ++i)
#pragma unroll
        for (int jj = 0; jj < 4; ++jj) acc[i][jj] = (f32x4){0.f, 0.f, 0.f, 0.f};

#pragma unroll
      for (int kt = 0; kt < 8; ++kt) {
        bf16x8 bfr[4];
#pragma unroll
        for (int nf = 0; nf < 4; ++nf)
          bfr[nf] = *(const bf16x8*)(WtQ + (size_t)(n0 + nf * 16 + lr) * 256 + kt * 32 + lkq * 8);
#pragma unroll
        for (int mf = 0; mf < 4; ++mf) {
          const int row = mf * 16 + lr;
          const int g = kt * 8 + lkq * 2;
          const f32x4 a0 = *(const f32x4*)(As + row * 256 + (((g    ) ^ (row & 7)) * 4));
          const f32x4 a1 = *(const f32x4*)(As + row * 256 + (((g + 1) ^ (row & 7)) * 4));
          bf16x8 af;
#pragma unroll
          for (int i = 0; i < 4; ++i) {
            af[i]     = f2bf_i(a0[i]);
            af[i + 4] = f2bf_i(a1[i]);
          }
#pragma unroll
          for (int nf = 0; nf < 4; ++nf)
            acc[mf][nf] = __builtin_amdgcn_mfma_f32_16x16x32_bf16(af, bfr[nf], acc[mf][nf], 0, 0, 0);
        }
      }

      float bv[4];
#pragma unroll
      for (int nf = 0; nf < 4; ++nf) {
        const int n = n0 + nf * 16 + lr;
        bv[nf] = (n < 256) ? b_off[n] : b_attn[n - 256];
      }
      const int lq4 = lkq * 4;
#pragma unroll
      for (int mf = 0; mf < 4; ++mf)
#pragma unroll
        for (int r = 0; r < 4; ++r) {
          const size_t m = m0 + mf * 16 + lq4 + r;
#pragma unroll
          for (int nf = 0; nf < 4; ++nf) {
            const int n = n0 + nf * 16 + lr;
            const float v = acc[mf][nf][r] + bv[nf];
            if (n < 256) offs[m * 256 + n] = v;
            else         logits[m * 128 + (n - 256)] = v;
          }
        }
    }
    __syncthreads();   // all waves done with As before phase 2 overwrites it
  }

  // ================= phase 2: persistent value GEMM (all blocks) ==========
  bf16x8 bfr[2][8];
#pragma unroll
  for (int nf = 0; nf < 2; ++nf) {
    const size_t bbase = (size_t)(w * 32 + nf * 16 + lr) * 256 + lkq * 8;
#pragma unroll
    for (int kt = 0; kt < 8; ++kt)
      bfr[nf][kt] = *(const bf16x8*)(WtV + bbase + kt * 32);
  }
  float bv[2];
#pragma unroll
  for (int nf = 0; nf < 2; ++nf) bv[nf] = b_val[w * 32 + nf * 16 + lr];

  auto stage = [&](int buf, int c) {
    const float* src = value + (size_t)c * (32 * 256);
#pragma unroll
    for (int i = 0; i < 4; ++i) {
      const int r = w * 4 + i;
      gld_lds16(src + r * 256 + ((lane ^ (r & 7)) * 4), As + buf * 8192 + r * 256);
    }
  };

  const int c0 = bid;
  stage(0, c0);
  asm volatile("s_waitcnt vmcnt(0)" ::: "memory");
  __syncthreads();

  int cb = 0;
  for (int c = c0; c < NCHUNK_; c += PSTRIDE_) {
    const int nxt = c + PSTRIDE_;
    if (nxt < NCHUNK_) stage(cb ^ 1, nxt);

    f32x4 acc[2][2];
#pragma unroll
    for (int i = 0; i < 2; ++i)
#pragma unroll
      for (int jj = 0; jj < 2; ++jj) acc[i][jj] = (f32x4){0.f, 0.f, 0.f, 0.f};

    const float* as = As + cb * 8192;
#pragma unroll
    for (int kt = 0; kt < 8; ++kt) {
      const int r0 = lr;
      const int r1 = 16 + lr;
      const int g = kt * 8 + lkq * 2;
      const f32x4 a00 = *(const f32x4*)(as + r0 * 256 + (((g    ) ^ (r0 & 7)) * 4));
      const f32x4 a01 = *(const f32x4*)(as + r0 * 256 + (((g + 1) ^ (r0 & 7)) * 4));
      const f32x4 a10 = *(const f32x4*)(as + r1 * 256 + (((g    ) ^ (r1 & 7)) * 4));
      const f32x4 a11 = *(const f32x4*)(as + r1 * 256 + (((g + 1) ^ (r1 & 7)) * 4));
      bf16x8 af0, af1;
#pragma unroll
      for (int i = 0; i < 4; ++i) {
        af0[i]     = f2bf_i(a00[i]);
        af0[i + 4] = f2bf_i(a01[i]);
        af1[i]     = f2bf_i(a10[i]);
        af1[i + 4] = f2bf_i(a11[i]);
      }
      acc[0][0] = __builtin_amdgcn_mfma_f32_16x16x32_bf16(af0, bfr[0][kt], acc[0][0], 0, 0, 0);
      acc[0][1] = __builtin_amdgcn_mfma_f32_16x16x32_bf16(af0, bfr[1][kt], acc[0][1], 0, 0, 0);
      acc[1][0] = __builtin_amdgcn_mfma_f32_16x16x32_bf16(af1, bfr[0][kt], acc[1][0], 0, 0, 0);
      acc[1][1] = __builtin_amdgcn_mfma_f32_16x16x32_bf16(af1, bfr[1][kt], acc[1][1], 0, 0, 0);
    }

#pragma unroll
    for (int mf = 0; mf < 2; ++mf)
#pragma unroll
      for (int rr = 0; rr < 4; ++rr) {
        const unsigned m = (unsigned)c * 32 + mf * 16 + lkq * 4 + rr;
        const unsigned b_ = m / LV_;
        const unsigned pos = m - b_ * LV_;
        const size_t rowbase = ((size_t)(b_ * HEADS_ + w) * LV_ + pos) * HEAD_DIM_;
#pragma unroll
        for (int nf = 0; nf < 2; ++nf)
          Vp[rowbase + nf * 16 + lr] = f2bf(acc[mf][nf][rr] + bv[nf]);
      }

    if (nxt < NCHUNK_) {
      asm volatile("s_waitcnt vmcnt(16)" ::: "memory");
      asm volatile("s_barrier" ::: "memory");
    }
    cb ^= 1;
  }
}

// ---------------------------------------------------------------------------
// Final output projection (R6 bigA structure, f32 out).
// ---------------------------------------------------------------------------
__global__ __launch_bounds__(256, 2) void gemm_qproj(
    const float* __restrict__ A, const short* __restrict__ Wt,
    const float* __restrict__ bias, float* __restrict__ C) {
  __shared__ float As[64 * 256];

  const int tid = threadIdx.x;
  const int lane = tid & 63;
  const int w = tid >> 6;
  const int n0 = w * 64;
  const size_t m0 = (size_t)blockIdx.x * 64;
  const int lr = lane & 15;
  const int lkq = lane >> 4;

#pragma unroll
  for (int i = 0; i < 16; ++i) {
    const int row = w * 16 + i;
    gld_lds16(A + (m0 + row) * 256 + ((lane ^ (row & 7)) * 4), As + row * 256);
  }

  bf16x8 bfr[4][8];
#pragma unroll
  for (int nf = 0; nf < 4; ++nf) {
    const size_t bbase = (size_t)(n0 + nf * 16 + lr) * 256 + lkq * 8;
#pragma unroll
    for (int kt = 0; kt < 8; ++kt)
      bfr[nf][kt] = *(const bf16x8*)(Wt + bbase + kt * 32);
  }

  f32x4 acc[4][4];
#pragma unroll
  for (int i = 0; i < 4; ++i)
#pragma unroll
    for (int jj = 0; jj < 4; ++jj) acc[i][jj] = (f32x4){0.f, 0.f, 0.f, 0.f};

  __syncthreads();

#pragma unroll
  for (int kt = 0; kt < 8; ++kt) {
#pragma unroll
    for (int mf = 0; mf < 4; ++mf) {
      const int row = mf * 16 + lr;
      const int gbase = kt * 8 + lkq * 2;
      const f32x4 a0 = *(const f32x4*)(As + row * 256 + ((gbase) ^ (row & 7)) * 4);
      const f32x4 a1 = *(const f32x4*)(As + row * 256 + ((gbase + 1) ^ (row & 7)) * 4);
      bf16x8 af;
#pragma unroll
      for (int i = 0; i < 4; ++i) {
        af[i]     = f2bf_i(a0[i]);
        af[i + 4] = f2bf_i(a1[i]);
      }
#pragma unroll
      for (int nf = 0; nf < 4; ++nf)
        acc[mf][nf] = __builtin_amdgcn_mfma_f32_16x16x32_bf16(af, bfr[nf][kt], acc[mf][nf], 0, 0, 0);
    }
  }

  float bv[4];
#pragma unroll
  for (int nf = 0; nf < 4; ++nf) bv[nf] = bias[n0 + nf * 16 + lr];
  const int lq4 = lkq * 4;
#pragma unroll
  for (int mf = 0; mf < 4; ++mf)
#pragma unroll
    for (int r = 0; r < 4; ++r) {
      const size_t m = m0 + mf * 16 + lq4 + r;
#pragma unroll
      for (int nf = 0; nf < 4; ++nf) {
        const int n = n0 + nf * 16 + lr;
        C[m * 256 + n] = acc[mf][nf][r] + bv[nf];
      }
    }
}

// ---------------------------------------------------------------------------
// Fused softmax + deformable sampling, 8-channel threads (max TLP).
// ---------------------------------------------------------------------------
__global__ __launch_bounds__(256) void msda_sample_fused(
    const float* __restrict__ ref_pts,   // [BS*LQ, 4, 2]
    const float* __restrict__ offsets,   // [BS*LQ, 256]  (h,l,p,2)
    const float* __restrict__ logits,    // [BS*LQ, 128]  (h,l,p)
    const short* __restrict__ value_p,   // [b,h,pos,32] bf16
    float* __restrict__ tmp)             // [BS*LQ, 256]
{
  const int t = blockIdx.x * 256 + threadIdx.x;
  const int c8 = t & 3;
  const int h = (t >> 2) & 7;
  const int row = t >> 5;
  const int b = row / LQ_;

  const int HS[4] = {100, 50, 25, 13};
  const int START[4] = {0, 10000, 12500, 13125};

  // ---- softmax over 16 logits, in-register ----
  const float* lg = logits + (size_t)row * 128 + h * 16;
  float wv[16];
  float mx = -1e30f;
#pragma unroll
  for (int i = 0; i < 4; ++i) {
    const f32x4 v = *(const f32x4*)(lg + i * 4);
#pragma unroll
    for (int jj = 0; jj < 4; ++jj) { wv[i * 4 + jj] = v[jj]; mx = fmaxf(mx, v[jj]); }
  }
  float sum = 0.f;
#pragma unroll
  for (int i = 0; i < 16; ++i) { wv[i] = __expf(wv[i] - mx); sum += wv[i]; }
  const float inv = 1.0f / sum;
#pragma unroll
  for (int i = 0; i < 16; ++i) wv[i] *= inv;

  const float* offr = offsets + (size_t)row * 256 + h * 32;
  const float* refr = ref_pts + (size_t)row * 8;

  float acc[8];
#pragma unroll
  for (int jj = 0; jj < 8; ++jj) acc[jj] = 0.f;

#pragma unroll
  for (int l = 0; l < 4; ++l) {
    const int HH = HS[l];
    const int WW = HS[l];
    const float fH = (float)HH, fW = (float)WW;
    const float rx = refr[l * 2 + 0];
    const float ry = refr[l * 2 + 1];
    const short* vbase =
        value_p + ((size_t)(b * HEADS_ + h) * LV_ + START[l]) * HEAD_DIM_ + c8 * 8;
#pragma unroll
    for (int p = 0; p < 4; ++p) {
      const float ox = offr[(l * 4 + p) * 2 + 0];
      const float oy = offr[(l * 4 + p) * 2 + 1];
      const float x = (rx + ox / fW) * fW - 0.5f;
      const float y = (ry + oy / fH) * fH - 0.5f;
      const float x0f = floorf(x), y0f = floorf(y);
      const float fx = x - x0f, fy = y - y0f;
      const int x0 = (int)x0f, y0 = (int)y0f;
      const float wgt = wv[l * 4 + p];
      const float iy0 = (y0 >= 0 && y0 < HH) ? 1.f : 0.f;
      const float iy1 = (y0 + 1 >= 0 && y0 + 1 < HH) ? 1.f : 0.f;
      const float ix0 = (x0 >= 0 && x0 < WW) ? 1.f : 0.f;
      const float ix1 = (x0 + 1 >= 0 && x0 + 1 < WW) ? 1.f : 0.f;
      const float w00 = (1.f - fy) * (1.f - fx) * wgt * iy0 * ix0;
      const float w01 = (1.f - fy) * fx * wgt * iy0 * ix1;
      const float w10 = fy * (1.f - fx) * wgt * iy1 * ix0;
      const float w11 = fy * fx * wgt * iy1 * ix1;
      const int xc0 = min(max(x0, 0), WW - 1);
      const int xc1 = min(max(x0 + 1, 0), WW - 1);
      const int yc0 = min(max(y0, 0), HH - 1);
      const int yc1 = min(max(y0 + 1, 0), HH - 1);
      const bf16x8 q00 = *(const bf16x8*)(vbase + (size_t)(yc0 * WW + xc0) * HEAD_DIM_);
      const bf16x8 q01 = *(const bf16x8*)(vbase + (size_t)(yc0 * WW + xc1) * HEAD_DIM_);
      const bf16x8 q10 = *(const bf16x8*)(vbase + (size_t)(yc1 * WW + xc0) * HEAD_DIM_);
      const bf16x8 q11 = *(const bf16x8*)(vbase + (size_t)(yc1 * WW + xc1) * HEAD_DIM_);
#pragma unroll
      for (int jj = 0; jj < 8; ++jj) {
        acc[jj] += w00 * bf2f(q00[jj]) + w01 * bf2f(q01[jj]) +
                   w10 * bf2f(q10[jj]) + w11 * bf2f(q11[jj]);
      }
    }
  }
  float* o = tmp + (size_t)row * 256 + h * 32 + c8 * 8;
  f32x4 o0 = {acc[0], acc[1], acc[2], acc[3]};
  f32x4 o1 = {acc[4], acc[5], acc[6], acc[7]};
  *(f32x4*)(o) = o0;
  *(f32x4*)(o + 4) = o1;
}

// ---------------------------------------------------------------------------
extern "C" void kernel_launch(void* const* d_in, const int* in_sizes, int n_in,
                              void* d_out, int out_size, void* d_ws, size_t ws_size,
                              hipStream_t stream) {
  const float* query  = (const float*)d_in[0];
  const float* refpts = (const float*)d_in[1];
  const float* value  = (const float*)d_in[2];
  const float* W_off  = (const float*)d_in[4];
  const float* b_off  = (const float*)d_in[5];
  const float* W_attn = (const float*)d_in[6];
  const float* b_attn = (const float*)d_in[7];
  const float* W_val  = (const float*)d_in[8];
  const float* b_val  = (const float*)d_in[9];
  const float* W_out  = (const float*)d_in[10];
  const float* b_out  = (const float*)d_in[11];
  float* out = (float*)d_out;

  // Dedicated workspace slots -- no aliasing. Total 242.7 MB.
  char* ws = (char*)d_ws;
  short* value_p = (short*)ws;                                 // 217,710,592 B
  size_t off = (size_t)BS_ * HEADS_ * LV_ * HEAD_DIM_ * 2;
  float* offsets = (float*)(ws + off); off += (size_t)BS_ * LQ_ * 256 * 4;  // 9.83 MB
  float* logits  = (float*)(ws + off); off += (size_t)BS_ * LQ_ * 128 * 4;  // 4.92 MB
  float* tmp     = (float*)(ws + off); off += (size_t)BS_ * LQ_ * 256 * 4;  // 9.83 MB
  short* WtQ = (short*)(ws + off); off += 384 * 256 * 2;                    // 192 KB
  short* WtV = (short*)(ws + off); off += 256 * 256 * 2;                    // 128 KB
  short* WtO = (short*)(ws + off); off += 256 * 256 * 2;                    // 128 KB

  const int MQ = BS_ * LQ_;   // 9600 = 64*150

  convert_all<<<896, 256, 0, stream>>>(W_off, W_attn, W_val, W_out, WtQ, WtV, WtO);
  mega_gemm<<<PSTRIDE_, 512, 0, stream>>>(value, WtV, b_val, value_p,
                                          query, WtQ, b_off, b_attn, offsets, logits);
  msda_sample_fused<<<(MQ * 32) / 256, 256, 0, stream>>>(refpts, offsets, logits, value_p, tmp);
  gemm_qproj<<<MQ / 64, 256, 0, stream>>>(tmp, WtO, b_out, out);
}